// Round 15
// baseline (32.591 us; speedup 1.0000x reference)
//
#include <hip/hip_runtime.h>
#include <hip/hip_bf16.h>

// LinearCombiner: MLP has NO activation -> affine: out = M@x + c,
// M = W3@W2@W1 (8x3072), c = (W3@W2)@b1 + W3@b2 + b3, and
// x[t,u] = [min;max;user] separable -> out[t,u,o] = P[t,o]+Q[u,o]+c[o].
//
// R14 structure (proven 32.55us) + R15 change (ONLY): GEMM A-reads from LDS
// via 3x ds_read_b128 per o (24 instr/thread) instead of 96x ds_read_b32.
// Broadcast pattern (half-wave same address) -> conflict-free. Accumulation
// order per acc[o] unchanged -> bit-identical numerics.
//  K1 (24x32): part1 = W3@W2 k-slice partials + cp2        [XCD-swizzled]
//  K2 (24x32): self-reduce M2 slice (L2-hot), part2 = M2@W1 + cp1 [swizzled]
//  K3 (97):    Mt reduce / M_user chunk reduce + user proj / c
//  K4 (256):   P[t] from Mt + Q = sum Qpart + c -> out row (1MB)

#define HIDN 3072
#define DIM 1024
#define NOUT 8
#define NS 32            // k-slices
#define KPS 96           // rows per slice
#define RPT 12           // rows per thread (KPS / 8 row-groups)
#define GX 24            // column groups of 128 cols
#define CPB 128          // cols per block (32 f4)
#define TDIM 256
#define UDIM 128
#define PF4 6144         // NOUT*HIDN/4 (f4 stride between slice partials)

__device__ __forceinline__ float4 f4z() { return make_float4(0.f, 0.f, 0.f, 0.f); }
__device__ __forceinline__ float4 add4(float4 a, float4 b) {
    return make_float4(a.x + b.x, a.y + b.y, a.z + b.z, a.w + b.w);
}
__device__ __forceinline__ float4 f4fma(float s, float4 v, float4 a) {
    return make_float4(fmaf(s, v.x, a.x), fmaf(s, v.y, a.y),
                       fmaf(s, v.z, a.z), fmaf(s, v.w, a.w));
}
__device__ __forceinline__ float dot4(float4 a, float4 b) {
    return a.x * b.x + a.y * b.y + a.z * b.z + a.w * b.w;
}

// fold cp[s][o] = sum_kk As[o][kk] * bvec[s*KPS+kk]  (32 lanes per o)
__device__ __forceinline__ void bias_slice_fold(const float* As,
                                                const float* __restrict__ bvec,
                                                float* __restrict__ cp,
                                                int s, int tid) {
    const int o = tid >> 5, k5 = tid & 31;
    float acc = 0.f;
#pragma unroll
    for (int j = 0; j < KPS / 32; ++j)
        acc += As[o * KPS + k5 + 32 * j] * bvec[s * KPS + k5 + 32 * j];
#pragma unroll
    for (int off = 16; off; off >>= 1) acc += __shfl_down(acc, off, 32);
    if (k5 == 0) cp[s * NOUT + o] = acc;
}

// mode 0: A_rows (8,HIDN) read directly. mode 1: A slice self-reduced from
// part_in. part_out[s][o][h] = sum_{k in slice s} A[o,k] * B[k,h]
// Block: 96 rows x 128 cols. Thread: rq = tid>>5 (12 rows), c4 = tid&31.
__global__ __launch_bounds__(256) void gemm_partial(
    const float* __restrict__ A_rows, const float* __restrict__ part_in,
    const float* __restrict__ B, float* __restrict__ part_out,
    const float* __restrict__ bvec, float* __restrict__ cp, int mode) {
    // ---- XCD-chunked swizzle: XCD k owns contiguous s-band [4k, 4k+4) ----
    const int orig = blockIdx.y * GX + blockIdx.x;        // hw linear id
    const int virt = (orig & 7) * 96 + (orig >> 3);       // bijective, 768=8*96
    const int s = virt / GX, gx = virt % GX;
    const int tid = threadIdx.x;
    const int rq = tid >> 5, c4 = tid & 31;

    __shared__ __align__(16) float As[NOUT * KPS];   // 3 KB
    __shared__ float4 red[8 * NOUT * 32];            // 32 KB: [rq][o][c4]

    if (mode == 0) {
        for (int i = tid; i < NOUT * KPS; i += 256)
            As[i] = A_rows[(i / KPS) * HIDN + s * KPS + (i % KPS)];
    } else {
        // As[o][kk] = sum_sp part_in[sp][o][s*KPS+kk]  (L2/L3-hot, f4)
        if (tid < NOUT * KPS / 4) {
            const int j4 = tid;
            const int o = j4 / (KPS / 4), kk4 = j4 % (KPS / 4);
            const float4* pp = (const float4*)(part_in + (size_t)o * HIDN
                                               + s * KPS) + kk4;
            float4 a = f4z();
#pragma unroll 8
            for (int sp = 0; sp < NS; ++sp)
                a = add4(a, pp[(size_t)sp * PF4]);
            ((float4*)As)[j4] = a;
        }
    }
    __syncthreads();
    if (gx == 0) bias_slice_fold(As, bvec, cp, s, tid);

    const int k0 = s * KPS + rq * RPT;
    const float4* Bp = (const float4*)(B + (size_t)k0 * HIDN) + gx * 32 + c4;

    float4 bv[RPT];                            // 12 hoisted loads, 12KB/wave
#pragma unroll
    for (int kk = 0; kk < RPT; ++kk) bv[kk] = Bp[(size_t)kk * (HIDN / 4)];

    // A from LDS as f4: row o = 24 f4, this thread's 12 rows = 3 f4 at rq*3
    const float4* As4 = (const float4*)As;
    float4 acc[NOUT];
#pragma unroll
    for (int o = 0; o < NOUT; ++o) acc[o] = f4z();
#pragma unroll
    for (int o = 0; o < NOUT; ++o) {
        const float4 a0 = As4[o * 24 + rq * 3 + 0];
        const float4 a1 = As4[o * 24 + rq * 3 + 1];
        const float4 a2 = As4[o * 24 + rq * 3 + 2];
        float4 r = acc[o];
        r = f4fma(a0.x, bv[0], r);  r = f4fma(a0.y, bv[1], r);
        r = f4fma(a0.z, bv[2], r);  r = f4fma(a0.w, bv[3], r);
        r = f4fma(a1.x, bv[4], r);  r = f4fma(a1.y, bv[5], r);
        r = f4fma(a1.z, bv[6], r);  r = f4fma(a1.w, bv[7], r);
        r = f4fma(a2.x, bv[8], r);  r = f4fma(a2.y, bv[9], r);
        r = f4fma(a2.z, bv[10], r); r = f4fma(a2.w, bv[11], r);
        acc[o] = r;
    }

    // cross-row-group reduce: red[rq][o][c4], then thread (o,c4) sums 8 rq
#pragma unroll
    for (int o = 0; o < NOUT; ++o) red[rq * 256 + o * 32 + c4] = acc[o];
    __syncthreads();
    {
        const int o = tid >> 5, cc = tid & 31;   // 256 threads = 8 o x 32 c4
        float4 r = f4z();
#pragma unroll
        for (int q = 0; q < 8; ++q) r = add4(r, red[q * 256 + o * 32 + cc]);
        *(float4*)(part_out + ((size_t)s * NOUT + o) * HIDN + gx * CPB + cc * 4) = r;
    }
}

// K3: b<64: Mt reduce ; b in [64,96): M_user chunk reduce + user projection ;
//     b==96: c.
__global__ __launch_bounds__(256) void k3_mid(
    const float* __restrict__ part2, const float* __restrict__ user,
    const float* __restrict__ cp1, const float* __restrict__ cp2,
    const float* __restrict__ b3, float* __restrict__ Mt,
    float* __restrict__ Qpart, float* __restrict__ cvec) {
    const int b = blockIdx.x, tid = threadIdx.x;
    const float4* p4 = (const float4*)part2;

    if (b < 64) {
        // Mt: 4096 f4 total; block owns 64 f4; 4 waves split 32 slices.
        const int lane = tid & 63, w = tid >> 6;
        const int i4 = b * 64 + lane;            // [0,4096): o = i4>>9, h4 = i4&511
        const int o = i4 >> 9, h4 = i4 & 511;
        float4 acc = f4z();
#pragma unroll
        for (int j = 0; j < 8; ++j)
            acc = add4(acc, p4[(size_t)(w * 8 + j) * PF4 + o * 768 + h4]);
        __shared__ float4 red2[4 * 64];
        red2[w * 64 + lane] = acc;
        __syncthreads();
        if (w == 0) {
            float4 r = add4(add4(red2[lane], red2[64 + lane]),
                            add4(red2[128 + lane], red2[192 + lane]));
            ((float4*)Mt)[i4] = r;
        }
        return;
    }

    if (b < 96) {
        // user chunk ub: cols4 [512+ub*8, +8) -> user dims [ub*32, +32)
        const int ub = b - 64;
        __shared__ float4 mup[4 * 64];
        __shared__ float4 Mu4[NOUT * 8];         // Mu[8][32] as f4
        const int tgt = tid & 63, grp = tid >> 6;
        const int o = tgt >> 3, j4 = tgt & 7;
        float4 a = f4z();
#pragma unroll
        for (int j = 0; j < 8; ++j)
            a = add4(a, p4[(size_t)(grp * 8 + j) * PF4 + o * 768 + 512 + ub * 8 + j4]);
        mup[grp * 64 + tgt] = a;
        __syncthreads();
        if (tid < 64)
            Mu4[tid] = add4(add4(mup[tid], mup[64 + tid]),
                            add4(mup[128 + tid], mup[192 + tid]));
        __syncthreads();

        const int u = tid >> 1, o0 = (tid & 1) * 4;
        const float4* uv = (const float4*)user + (size_t)u * (DIM / 4) + ub * 8;
        float4 x8[8];
#pragma unroll
        for (int j = 0; j < 8; ++j) x8[j] = uv[j];
        float q[4];
#pragma unroll
        for (int oo = 0; oo < 4; ++oo) {
            float s = 0.f;
#pragma unroll
            for (int j = 0; j < 8; ++j) s += dot4(Mu4[(o0 + oo) * 8 + j], x8[j]);
            q[oo] = s;
        }
        ((float4*)Qpart)[((size_t)ub * UDIM + u) * 2 + (tid & 1)] =
            make_float4(q[0], q[1], q[2], q[3]);
        return;
    }

    if (tid < NOUT) {                            // b == 96: c
        float cc = b3[tid];
#pragma unroll 8
        for (int s = 0; s < NS; ++s)
            cc += cp1[s * NOUT + tid] + cp2[s * NOUT + tid];
        cvec[tid] = cc;
    }
}

// K4: out[t,u,:] = P[t] + sum_ub Qpart[ub][u] + c   (256 t-blocks)
__global__ __launch_bounds__(256) void k4_out(
    const float* __restrict__ ta, const float* __restrict__ tb,
    const float* __restrict__ Mt, const float* __restrict__ Qpart,
    const float* __restrict__ cvec, float4* __restrict__ out) {
    const int t = blockIdx.x, tid = threadIdx.x;
    const int lane = tid & 63, w = tid >> 6;

    const float4* Mt4 = (const float4*)Mt;
    float4 a = ((const float4*)ta)[(size_t)t * (DIM / 4) + tid];
    float4 b = ((const float4*)tb)[(size_t)t * (DIM / 4) + tid];
    float4 mn = make_float4(fminf(a.x, b.x), fminf(a.y, b.y),
                            fminf(a.z, b.z), fminf(a.w, b.w));
    float4 mx = make_float4(fmaxf(a.x, b.x), fmaxf(a.y, b.y),
                            fmaxf(a.z, b.z), fmaxf(a.w, b.w));
    float acc[NOUT];
#pragma unroll
    for (int o = 0; o < NOUT; ++o) {
        float4 ml = Mt4[o * 512 + tid];          // dims 0..1023 (min half)
        float4 mh = Mt4[o * 512 + 256 + tid];    // dims 1024..2047 (max half)
        acc[o] = dot4(ml, mn) + dot4(mh, mx);
    }
#pragma unroll
    for (int o = 0; o < NOUT; ++o) {
#pragma unroll
        for (int off = 32; off > 0; off >>= 1)
            acc[o] += __shfl_down(acc[o], off, 64);
    }
    __shared__ float red[4][NOUT];
    if (lane == 0) {
#pragma unroll
        for (int o = 0; o < NOUT; ++o) red[w][o] = acc[o];
    }
    __syncthreads();

    const int u = tid >> 1, half = tid & 1, o0 = half * 4;
    const float4* Qp4 = (const float4*)Qpart;
    float4 q = f4z();
#pragma unroll 8
    for (int ub = 0; ub < 32; ++ub)
        q = add4(q, Qp4[((size_t)ub * UDIM + u) * 2 + half]);

    float4 cv = ((const float4*)cvec)[half];
    float4 pv = make_float4(
        red[0][o0 + 0] + red[1][o0 + 0] + red[2][o0 + 0] + red[3][o0 + 0],
        red[0][o0 + 1] + red[1][o0 + 1] + red[2][o0 + 1] + red[3][o0 + 1],
        red[0][o0 + 2] + red[1][o0 + 2] + red[2][o0 + 2] + red[3][o0 + 2],
        red[0][o0 + 3] + red[1][o0 + 3] + red[2][o0 + 3] + red[3][o0 + 3]);
    out[(size_t)t * 256 + tid] = add4(add4(pv, q), cv);
}

extern "C" void kernel_launch(void* const* d_in, const int* in_sizes, int n_in,
                              void* d_out, int out_size, void* d_ws, size_t ws_size,
                              hipStream_t stream) {
    const float* text_a = (const float*)d_in[0];
    const float* text_b = (const float*)d_in[1];
    const float* user   = (const float*)d_in[2];
    const float* W1 = (const float*)d_in[3];
    const float* b1 = (const float*)d_in[4];
    const float* W2 = (const float*)d_in[5];
    const float* b2 = (const float*)d_in[6];
    const float* W3 = (const float*)d_in[7];
    const float* b3 = (const float*)d_in[8];

    float* ws = (float*)d_ws;
    float* part1 = ws;                                  // 786432 floats
    float* part2 = part1 + (size_t)NS * NOUT * HIDN;    // 786432
    float* Mt    = part2 + (size_t)NS * NOUT * HIDN;    // 16384 (8x2048)
    float* Qpart = Mt + NOUT * 2048;                    // 32768 (32x128x8)
    float* cp1   = Qpart + 32 * UDIM * NOUT;            // 256
    float* cp2   = cp1 + NS * NOUT;                     // 256
    float* cvec  = cp2 + NS * NOUT;                     // 8

    // K1: part1 = W3 @ W2 ; cp2
    gemm_partial<<<dim3(GX, NS), 256, 0, stream>>>(W3, nullptr, W2, part1,
                                                   b2, cp2, 0);
    // K2: As = M2 slice (self-reduce from part1) ; part2 = M2 @ W1 ; cp1
    gemm_partial<<<dim3(GX, NS), 256, 0, stream>>>(nullptr, part1, W1, part2,
                                                   b1, cp1, 1);
    // K3: Mt reduce + Qpart projection + c
    k3_mid<<<97, 256, 0, stream>>>(part2, user, cp1, cp2, b3, Mt, Qpart, cvec);
    // K4: out
    k4_out<<<TDIM, 256, 0, stream>>>(text_a, text_b, Mt, Qpart, cvec,
                                     (float4*)d_out);
}